// Round 12
// baseline (210.754 us; speedup 1.0000x reference)
//
#include <hip/hip_runtime.h>
#include <cstdint>
#include <cstddef>

#define BATCH 8192
#define DIN   1025
#define HID   1024
#define NACT  1026
#define NHEAD 513
#define KSEL  32
#define KP0   1088   /* DIN padded to multiple of 64 (W0t leading dim) */
#define LGN   1024   /* logits cols 0..1023 via GEMM; 1024/1025 computed in sample */

typedef unsigned short u16;
typedef short bf16x8 __attribute__((ext_vector_type(8)));
typedef float f32x4 __attribute__((ext_vector_type(4)));

__device__ __forceinline__ u16 f2bf(float f) {
  unsigned u = __float_as_uint(f);
  u += 0x7fff + ((u >> 16) & 1);   // round-to-nearest-even
  return (u16)(u >> 16);
}
__device__ __forceinline__ float bf2f(u16 h) {
  return __uint_as_float((unsigned)h << 16);
}

__device__ __forceinline__ void async_cp16(const u16* g, u16* l) {
  __builtin_amdgcn_global_load_lds((const __attribute__((address_space(1))) void*)g,
                                   (__attribute__((address_space(3))) void*)l,
                                   16, 0, 0);
}
__device__ __forceinline__ void async_cp4(const float* g, float* l) {
  __builtin_amdgcn_global_load_lds((const __attribute__((address_space(1))) void*)g,
                                   (__attribute__((address_space(3))) void*)l,
                                   4, 0, 0);
}

// ---------------- weight conversion (512 thr, grid 3137) ----------------
// One 32x32 transpose tile per block: W0t 1088 tiles, W1t 1024, W2t 1024, W2c 1.
__global__ __launch_bounds__(512) void k_wcvt(
    const float* __restrict__ W0, const float* __restrict__ W1,
    const float* __restrict__ W2,
    u16* __restrict__ W0t, u16* __restrict__ W1t,
    u16* __restrict__ W2t, u16* __restrict__ W2c) {
  const int tid = threadIdx.x;
  const int b = blockIdx.x;
  if (b == 3136) {   // W2 cols 1024,1025 -> W2c[2][1024]
    for (int e = tid; e < 2048; e += 512) {
      int j = e >> 10, k = e & 1023;
      W2c[e] = f2bf(W2[(size_t)k * NACT + 1024 + j]);
    }
    return;
  }
  const float* W; u16* Wt; int K, ldW, Kp, tt = b;
  if (tt < 1088)      { W = W0; Wt = W0t; K = DIN; ldW = HID;  Kp = KP0; }
  else if (tt < 2112) { tt -= 1088; W = W1; Wt = W1t; K = HID; ldW = HID;  Kp = HID; }
  else                { tt -= 2112; W = W2; Wt = W2t; K = HID; ldW = NACT; Kp = HID; }
  int n0 = (tt & 31) * 32, k0 = (tt >> 5) * 32;
  __shared__ float tile[32][33];
  const int tx = tid & 31, ty = tid >> 5;   // ty 0..15
#pragma unroll
  for (int i = 0; i < 32; i += 16) {
    int k = k0 + ty + i;
    tile[ty + i][tx] = (k < K) ? W[(size_t)k * ldW + n0 + tx] : 0.f;
  }
  __syncthreads();
#pragma unroll
  for (int i = 0; i < 32; i += 16)
    Wt[(size_t)(n0 + ty + i) * Kp + k0 + tx] = f2bf(tile[tx][ty + i]);
}

// ---- GEMM1: C = relu(state_f32 @ W0 + b0), A staged as f32 on the fly ----------
// Block tile 128x256, 8 waves (2x4) of 64x64, BK=32, K-loop 32 iters (k 0..1023);
// k=1024 added as rank-1 epilogue fixup (avoids OOB on the 1025-stride rows).
// A staged via global_load_lds width=4 (rows are 4-byte aligned only), converted
// f32->bf16 in-register post-ds_read (VALU co-issues with MFMA, m114).
// XOR chunk swizzle on both A (4-dword chunks ^ row&7) and B (r11 scheme) keeps
// ds_read_b128 at <=2-way. Dbuf RAW s_barrier + vmcnt(10) pipeline (10 staging
// insts/thread/iter: 8 A-dword + 2 B-dwordx4).
__global__ __launch_bounds__(512, 1)
void gemm1_f32a(const float* __restrict__ A, const u16* __restrict__ Bt,
                const float* __restrict__ bias, u16* __restrict__ Cout)
{
  __shared__ __align__(16) u16 lds[32768];   // 64 KB: 2 bufs x (A f32 16KB + B bf16 16KB)

  const int d     = blockIdx.x;
  const int ntile = (d >> 3) & 3;
  const int mtile = ((d >> 5) << 3) | (d & 7);
  const size_t bm = (size_t)mtile * 128;
  const size_t bn = (size_t)ntile * 256;

  const int tid  = threadIdx.x;
  const int wave = tid >> 6;
  const int lane = tid & 63;
  const int waveM = wave >> 2, waveN = wave & 3;
  const int lr = lane & 15, lq = lane >> 4;

  // A staging map: 4096 dwords/tile; inst j covers dword dd = j*512 + tid.
  // row = dd>>5, kslot = dd&31; global k = ((kslot>>2 ^ (row&7))<<2) | (kslot&3)
  const float* aSrc[8];
#pragma unroll
  for (int j = 0; j < 8; ++j) {
    int dd = j * 512 + tid;
    int row = dd >> 5, kslot = dd & 31;
    int gk = ((((kslot >> 2) ^ (row & 7))) << 2) | (kslot & 3);
    aSrc[j] = A + (bm + row) * (size_t)DIN + gk;
  }
  // B staging: 1024 chunks of 16B; c = tid, tid+512; row=c>>2, g=(c&3)^((row>>1)&3)
  const int rowB0 = tid >> 2;
  const int gB0_  = (tid & 3) ^ ((rowB0 >> 1) & 3);
  const int rowB1 = rowB0 + 128;
  const int gB1_  = (tid & 3) ^ ((rowB1 >> 1) & 3);
  const u16* gB0 = Bt + (bn + rowB0) * (size_t)KP0 + gB0_ * 8;
  const u16* gB1 = Bt + (bn + rowB1) * (size_t)KP0 + gB1_ * 8;

  f32x4 acc[4][4] = {};

  const int sB = lq ^ ((lr >> 1) & 3);

  auto issue = [&](int k0, int buf) {
    u16* base = lds + buf * 16384;
    float* af = (float*)base;
#pragma unroll
    for (int j = 0; j < 8; ++j)
      async_cp4(aSrc[j] + k0, af + j * 512 + wave * 64);   // wave-uniform dst + lane*4B
    u16* bb = base + 8192;
    async_cp16(gB0 + k0, bb + wave * 512);
    async_cp16(gB1 + k0, bb + 4096 + wave * 512);
  };

  const int NIT = 32;
  issue(0, 0);
  for (int it = 0; it < NIT; ++it) {
    const int buf = it & 1;
    if (it + 1 < NIT) {
      issue((it + 1) * 32, buf ^ 1);
      asm volatile("s_waitcnt vmcnt(10)\n\ts_barrier" ::: "memory");
    } else {
      asm volatile("s_waitcnt vmcnt(0)\n\ts_barrier" ::: "memory");
    }

    const u16* base = lds + buf * 16384;
    bf16x8 af[4], bf[4];
#pragma unroll
    for (int t = 0; t < 4; ++t) {
      int row = waveM * 64 + t * 16 + lr;
      int c0 = (2 * lq) ^ (row & 7);
      int c1 = (2 * lq + 1) ^ (row & 7);
      f32x4 fa0 = *(const f32x4*)(base + row * 64 + c0 * 8);
      f32x4 fa1 = *(const f32x4*)(base + row * 64 + c1 * 8);
      bf16x8 v;
      v[0] = (short)f2bf(fa0[0]); v[1] = (short)f2bf(fa0[1]);
      v[2] = (short)f2bf(fa0[2]); v[3] = (short)f2bf(fa0[3]);
      v[4] = (short)f2bf(fa1[0]); v[5] = (short)f2bf(fa1[1]);
      v[6] = (short)f2bf(fa1[2]); v[7] = (short)f2bf(fa1[3]);
      af[t] = v;
    }
    const u16* pb = base + 8192 + (waveN * 64 + lr) * 32 + sB * 8;
#pragma unroll
    for (int t = 0; t < 4; ++t) bf[t] = *(const bf16x8*)(pb + t * 512);
#pragma unroll
    for (int tm = 0; tm < 4; ++tm)
#pragma unroll
      for (int tn = 0; tn < 4; ++tn)
        acc[tm][tn] = __builtin_amdgcn_mfma_f32_16x16x32_bf16(af[tm], bf[tn], acc[tm][tn], 0, 0, 0);

    asm volatile("s_waitcnt lgkmcnt(0)\n\ts_barrier" ::: "memory");
  }

  // rank-1 fixup for k=1024 (valid data; W0t k>=1025 is zero so MFMA part is exact)
  float afix[4][4], bfix[4];
#pragma unroll
  for (int tm = 0; tm < 4; ++tm)
#pragma unroll
    for (int r = 0; r < 4; ++r)
      afix[tm][r] = A[(bm + waveM * 64 + tm * 16 + lq * 4 + r) * (size_t)DIN + 1024];
#pragma unroll
  for (int tn = 0; tn < 4; ++tn)
    bfix[tn] = bf2f(Bt[(bn + waveN * 64 + tn * 16 + lr) * (size_t)KP0 + 1024]);

  // epilogue: D row = lq*4 + r, col = lr (m89-verified layout)
#pragma unroll
  for (int tm = 0; tm < 4; ++tm) {
    size_t rw = bm + waveM * 64 + tm * 16 + lq * 4;
#pragma unroll
    for (int tn = 0; tn < 4; ++tn) {
      int col = (int)bn + waveN * 64 + tn * 16 + lr;
      float bv = bias[col];
#pragma unroll
      for (int r = 0; r < 4; ++r) {
        float v = acc[tm][tn][r] + afix[tm][r] * bfix[tn] + bv;
        v = fmaxf(v, 0.f);
        Cout[(rw + r) * HID + col] = f2bf(v);
      }
    }
  }
}

// ---- GEMM2/3 (bf16 A): r11-measured-best structure, unchanged --------------------
// Block tile 128x256, 8 waves of 64x64, BK=32, dbuf 2x24KB, RAW s_barrier +
// vmcnt(3), XCD swizzle, XOR bank swizzle.
template<bool RELU, int K>
__global__ __launch_bounds__(512, 2)
void gemm_bt(const u16* __restrict__ A, const u16* __restrict__ Bt,
             const float* __restrict__ bias, u16* __restrict__ Cout, int ldc)
{
  __shared__ __align__(16) u16 lds[24576];   // 48 KB

  const int d     = blockIdx.x;
  const int ntile = (d >> 3) & 3;
  const int mtile = ((d >> 5) << 3) | (d & 7);
  const size_t bm = (size_t)mtile * 128;
  const size_t bn = (size_t)ntile * 256;

  const int tid  = threadIdx.x;
  const int wave = tid >> 6;
  const int lane = tid & 63;
  const int waveM = wave >> 2, waveN = wave & 3;
  const int lr = lane & 15, lq = lane >> 4;

  const int rowA  = tid >> 2;
  const int gA_   = (tid & 3) ^ ((rowA >> 1) & 3);
  const int rowB0 = tid >> 2;
  const int gB0_  = (tid & 3) ^ ((rowB0 >> 1) & 3);
  const int rowB1 = rowB0 + 128;
  const int gB1_  = (tid & 3) ^ ((rowB1 >> 1) & 3);
  const u16* gA  = A  + (bm + rowA)  * (size_t)K + gA_  * 8;
  const u16* gB0 = Bt + (bn + rowB0) * (size_t)K + gB0_ * 8;
  const u16* gB1 = Bt + (bn + rowB1) * (size_t)K + gB1_ * 8;
  u16* lA  = lds + wave * 512;
  u16* lB0 = lds + 4096 + wave * 512;
  u16* lB1 = lB0 + 4096;

  f32x4 acc[4][4] = {};

  const int s = lq ^ ((lr >> 1) & 3);
  const u16* pa = lds + (waveM * 64 + lr) * 32 + s * 8;
  const u16* pb = lds + 4096 + (waveN * 64 + lr) * 32 + s * 8;

  auto issue = [&](int k0, int buf) {
    const int o = buf * 12288;
    async_cp16(gA  + k0, lA  + o);
    async_cp16(gB0 + k0, lB0 + o);
    async_cp16(gB1 + k0, lB1 + o);
  };

  const int NIT = K / 32;
  issue(0, 0);
#pragma unroll 2
  for (int it = 0; it < NIT; ++it) {
    const int buf = it & 1;
    if (it + 1 < NIT) {
      issue((it + 1) * 32, buf ^ 1);
      asm volatile("s_waitcnt vmcnt(3)\n\ts_barrier" ::: "memory");
    } else {
      asm volatile("s_waitcnt vmcnt(0)\n\ts_barrier" ::: "memory");
    }

    bf16x8 af[4], bf[4];
    const u16* qa = pa + buf * 12288;
    const u16* qb = pb + buf * 12288;
#pragma unroll
    for (int t = 0; t < 4; ++t) {
      af[t] = *(const bf16x8*)(qa + t * 512);
      bf[t] = *(const bf16x8*)(qb + t * 512);
    }
#pragma unroll
    for (int tm = 0; tm < 4; ++tm)
#pragma unroll
      for (int tn = 0; tn < 4; ++tn)
        acc[tm][tn] = __builtin_amdgcn_mfma_f32_16x16x32_bf16(af[tm], bf[tn], acc[tm][tn], 0, 0, 0);

    asm volatile("s_waitcnt lgkmcnt(0)\n\ts_barrier" ::: "memory");
  }

#pragma unroll
  for (int tm = 0; tm < 4; ++tm) {
    size_t rw = bm + waveM * 64 + tm * 16 + lq * 4;
#pragma unroll
    for (int tn = 0; tn < 4; ++tn) {
      int col = (int)bn + waveN * 64 + tn * 16 + lr;
      float bv = bias[col];
#pragma unroll
      for (int r = 0; r < 4; ++r) {
        float v = acc[tm][tn][r] + bv;
        if (RELU) v = fmaxf(v, 0.f);
        Cout[(rw + r) * ldc + col] = f2bf(v);
      }
    }
  }
}

// ---------------- sampling (512 thr, grid 2048; 4 rows/block) --------------------
__global__ __launch_bounds__(512) void k_sample(const u16* __restrict__ lgts,
    const u16* __restrict__ h2, const u16* __restrict__ W2c,
    const float* __restrict__ b2,
    const int* __restrict__ idxR, const int* __restrict__ lenR,
    const int* __restrict__ idxS, const int* __restrict__ lenS,
    float* __restrict__ out) {
  __shared__ float shf[16];
  const int tid = threadIdx.x;
  const int w = tid >> 6, lane = tid & 63;
  const int grp = w & 1, pair = w >> 1;
  const int row = blockIdx.x * 4 + pair;
  const u16* base = lgts + (size_t)row * LGN + (grp ? NHEAD : 0);
  const int* sidx = (grp ? idxS : idxR) + (size_t)row * KSEL;
  const int slen  = (grp ? lenS : lenR)[row];

  float x1024 = 0.f, x1025 = 0.f;
  if (grp) {
    float d0 = 0.f, d1 = 0.f;
    const u16* hr  = h2 + (size_t)row * HID + lane * 16;
    const u16* w0p = W2c + lane * 16;
    const u16* w1p = W2c + 1024 + lane * 16;
#pragma unroll
    for (int j = 0; j < 16; ++j) {
      float h = bf2f(hr[j]);
      d0 += h * bf2f(w0p[j]);
      d1 += h * bf2f(w1p[j]);
    }
#pragma unroll
    for (int dd = 32; dd; dd >>= 1) { d0 += __shfl_xor(d0, dd, 64); d1 += __shfl_xor(d1, dd, 64); }
    x1024 = d0 + b2[1024];
    x1025 = d1 + b2[1025];
  }
  const int NHm = grp ? 511 : 513;

  float m = -3.4e38f;
  for (int i = lane; i < NHm; i += 64) m = fmaxf(m, bf2f(base[i]));
  if (grp) {
    if (lane == 63) m = fmaxf(m, x1024);
    if (lane == 0)  m = fmaxf(m, x1025);
  }
#pragma unroll
  for (int dd = 32; dd; dd >>= 1) m = fmaxf(m, __shfl_xor(m, dd, 64));

  float S = 0.f, T = 0.f;
  for (int i = lane; i < NHm; i += 64) {
    float xi = bf2f(base[i]);
    float e = __expf(xi - m);
    S += e; T += e * xi;
  }
  if (grp) {
    if (lane == 63) { float e = __expf(x1024 - m); S += e; T += e * x1024; }
    if (lane == 0)  { float e = __expf(x1025 - m); S += e; T += e * x1025; }
  }
#pragma unroll
  for (int dd = 32; dd; dd >>= 1) { S += __shfl_xor(S, dd, 64); T += __shfl_xor(T, dd, 64); }

  float e = 0.f, ex = 0.f, xt = 0.f;
  int active = (lane < KSEL) && (lane < slen);
  int valid = 0;
  if (active) {
    int id = sidx[lane];
    if (id >= 0) {
      valid = 1;
      if (grp && id >= 511) xt = (id == 511) ? x1024 : x1025;
      else                  xt = bf2f(base[id]);
      e  = __expf(xt - m);
      ex = e * xt;
    }
  }
  float pe = e, pex = ex;
#pragma unroll
  for (int dd = 1; dd < 32; dd <<= 1) {
    float qa = __shfl_up(pe, dd, 64);
    float qb = __shfl_up(pex, dd, 64);
    if (lane >= dd) { pe += qa; pex += qb; }
  }
  float lp = 0.f, en = 0.f;
  if (active) {
    float St = S - (pe - e);
    float Tt = T - (pex - ex);
    float logZ = m + __logf(St);
    en = logZ - Tt / St;
    if (valid) lp = xt - logZ;
  }
#pragma unroll
  for (int dd = 32; dd; dd >>= 1) { lp += __shfl_xor(lp, dd, 64); en += __shfl_xor(en, dd, 64); }

  if (lane == 0) { shf[w * 2] = lp; shf[w * 2 + 1] = en; }
  __syncthreads();
  if (lane == 0 && grp == 0) {
    out[row]         = shf[pair * 4] + shf[pair * 4 + 2];
    out[BATCH + row] = shf[pair * 4 + 1] + shf[pair * 4 + 3];
  }
}

// ---------------- launch ----------------
extern "C" void kernel_launch(void* const* d_in, const int* in_sizes, int n_in,
                              void* d_out, int out_size, void* d_ws, size_t ws_size,
                              hipStream_t stream) {
  (void)in_sizes; (void)n_in; (void)out_size; (void)ws_size;
  const float* state = (const float*)d_in[0];
  const float* W0 = (const float*)d_in[1];
  const float* b0 = (const float*)d_in[2];
  const float* W1 = (const float*)d_in[3];
  const float* b1 = (const float*)d_in[4];
  const float* W2 = (const float*)d_in[5];
  const float* b2 = (const float*)d_in[6];
  const int* idxR = (const int*)d_in[7];
  const int* lenR = (const int*)d_in[8];
  const int* idxS = (const int*)d_in[9];
  const int* lenS = (const int*)d_in[10];
  float* out = (float*)d_out;

  char* ws = (char*)d_ws;
  size_t off = 0;
  auto alloc = [&](size_t bytes) -> char* {
    char* p = ws + off;
    off = (off + bytes + 255) & ~(size_t)255;
    return p;
  };
  u16* W0t  = (u16*)alloc((size_t)HID * KP0 * 2);     //  2.2 MB
  u16* W1t  = (u16*)alloc((size_t)HID * HID * 2);     //  2.1 MB
  u16* W2t  = (u16*)alloc((size_t)HID * LGN * 2);     //  2.1 MB
  u16* W2c  = (u16*)alloc((size_t)2 * 1024 * 2);      //  4 KB
  u16* h1   = (u16*)alloc((size_t)BATCH * HID * 2);   // 16.8 MB
  u16* h2   = (u16*)alloc((size_t)BATCH * HID * 2);   // 16.8 MB
  u16* lgts = (u16*)alloc((size_t)BATCH * LGN * 2);   // 16.8 MB

  k_wcvt<<<3137, 512, 0, stream>>>(W0, W1, W2, W0t, W1t, W2t, W2c);

  gemm1_f32a        <<<256, 512, 0, stream>>>(state, W0t, b0, h1);
  gemm_bt<true, HID><<<256, 512, 0, stream>>>(h1, W1t, b1, h2,   HID);
  gemm_bt<false,HID><<<256, 512, 0, stream>>>(h2, W2t, b2, lgts, LGN);

  k_sample<<<2048, 512, 0, stream>>>(lgts, h2, W2c, b2, idxR, lenR, idxS, lenS, out);
}